// Round 7
// baseline (2815.269 us; speedup 1.0000x reference)
//
#include <hip/hip_runtime.h>

// Residual VQ forward (eval): x [16,2048,256] f32, embeddings [8,1024,256] f32
// outputs concat: quantized [N*D], loss [1], codes [N*L] (as float)
// N = 32768, D = 256, L = 8, K = 1024.
//
// 1 block = 32 rows, 256 threads, 2 blocks/CU (78.4 KB LDS).
// Per layer: distance GEMM (32x1024x256) with 8x4 per-thread tile.
// Waves are row-uniform (ty = tid>>6) -> rv LDS reads are wave broadcasts.
// Et double-buffered (2 x 256 x 16 d-slice), reg-prefetched 2 chunks ahead
// (T14 async-stage), ONE barrier per chunk.
// quantized_out = x - residual_final (telescoped).

#define NL 8
#define NK 1024
#define ND 256
#define NROWTOT 32768
#define ROWS 32
#define RSTR 260    // 256+4: stride 65 f4-slots == 1 mod 8 -> conflict-free epilogue
#define KT 256      // k-rows per Et buffer
#define DT 16       // d-slice per chunk
#define ESTR 20     // 16+4: stride 5 f4-slots -> perfect 8-quad spread on ev reads

// ---------------------------------------------------------------- prologue ---
__global__ __launch_bounds__(256)
void enorm_zero_kernel(const float* __restrict__ emb, float* __restrict__ enorm,
                       float* __restrict__ loss_slot) {
    // 8192 codebook rows, 256 blocks x 32 rows, 8 lanes per row
    int row = blockIdx.x * 32 + (threadIdx.x >> 3);
    int l8  = threadIdx.x & 7;
    const float4* e4 = (const float4*)(emb + (size_t)row * ND);
    float s = 0.f;
#pragma unroll
    for (int q = 0; q < 8; ++q) {
        float4 v = e4[q * 8 + l8];
        s = fmaf(v.x, v.x, s); s = fmaf(v.y, v.y, s);
        s = fmaf(v.z, v.z, s); s = fmaf(v.w, v.w, s);
    }
    s += __shfl_xor(s, 1);
    s += __shfl_xor(s, 2);
    s += __shfl_xor(s, 4);
    if (l8 == 0) enorm[row] = s;
    if (blockIdx.x == 0 && threadIdx.x == 0) *loss_slot = 0.f;  // d_out poisoned 0xAA
}

// -------------------------------------------------------------------- main ---
__global__ __launch_bounds__(256, 2)
void rvq_kernel(const float* __restrict__ x, const float* __restrict__ emb,
                const float* __restrict__ enorm, float* __restrict__ out) {
    __shared__ float R[ROWS][RSTR];       // 33280 B residual tile
    __shared__ float Et[2][KT][ESTR];     // 40960 B double-buffered codebook slice
    __shared__ float En[NK];              //  4096 B ||e||^2 for current layer
    __shared__ int   amin[ROWS];
    __shared__ float lred[4];

    const int tid   = threadIdx.x;
    const int tx    = tid & 63;        // k lane (whole wave)
    const int ty    = tid >> 6;        // wave id = row group (rows ty*8..ty*8+7)
    const int row_e = tid >> 3;        // epilogue row 0..31
    const int dq    = tid & 7;         // epilogue lane-in-row
    const int sk    = tid >> 2;        // staging row base (0..63)
    const int sq    = tid & 3;         // staging quad-in-row (0..3)
    const int brow  = blockIdx.x * ROWS;

    float* loss_slot = out + (size_t)NROWTOT * ND;
    float* codes     = loss_slot + 1;

    // load x tile into LDS residual
    const float4* x4 = (const float4*)(x + (size_t)(brow + row_e) * ND);
#pragma unroll
    for (int q = 0; q < 8; ++q) {
        int qq = q * 8 + dq;
        *(float4*)&R[row_e][qq * 4] = x4[qq];
    }

    // chunk g (0..511): l = g>>6, kc = (g>>4)&3, dc = g&15
    // Et buffer g&1 holds chunk g's 256x16 slice; stage regs hold chunk g+1.
    const float4* emb4 = (const float4*)emb;   // layer stride 65536 float4
    float4 stage[4];
    // chunk 0 -> Et[0]
#pragma unroll
    for (int p = 0; p < 4; ++p)
        stage[p] = emb4[(size_t)(p * 64 + sk) * 64 + sq];
#pragma unroll
    for (int p = 0; p < 4; ++p)
        *(float4*)&Et[0][p * 64 + sk][sq * 4] = stage[p];
    // prefetch chunk 1 (l=0,kc=0,dc=1)
#pragma unroll
    for (int p = 0; p < 4; ++p)
        stage[p] = emb4[(size_t)(p * 64 + sk) * 64 + 4 + sq];

    float loss_acc = 0.f;

    for (int l = 0; l < NL; ++l) {
        // stage ||e||^2 (first read many barriers later; writes disjoint per thread)
        const float* enl = enorm + l * NK;
#pragma unroll
        for (int p = 0; p < 4; ++p) En[tid + p * 256] = enl[tid + p * 256];

        float minv[8];
        int   mini[8];
#pragma unroll
        for (int i = 0; i < 8; ++i) { minv[i] = 3.4e38f; mini[i] = 0; }

        float acc[8][4];

        for (int cc = 0; cc < 64; ++cc) {        // cc = kc*16 + dc
            const int g   = l * 64 + cc;         // global chunk
            const int kc  = cc >> 4, dc = cc & 15;
            const int buf = g & 1;

            __syncthreads();  // all reads of Et[buf^1] (chunk g-1) and, at layer
                              // start, epilogue R-writes / prologue commits done
            // commit prefetched chunk g+1 -> Et[buf^1]
#pragma unroll
            for (int p = 0; p < 4; ++p)
                *(float4*)&Et[buf ^ 1][p * 64 + sk][sq * 4] = stage[p];
            // issue prefetch of chunk g+2 (consumed two chunks from now)
            {
                int gp = g + 2; if (gp > 511) gp = 511;
                const int lp = gp >> 6, kcp = (gp >> 4) & 3, dcp = gp & 15;
                const size_t base = (size_t)lp * 65536
                                  + (size_t)(kcp * KT + sk) * 64
                                  + (size_t)dcp * 4 + sq;
#pragma unroll
                for (int p = 0; p < 4; ++p)
                    stage[p] = emb4[base + (size_t)(p * 64) * 64];
            }
            if (dc == 0) {
#pragma unroll
                for (int i = 0; i < 8; ++i)
#pragma unroll
                    for (int j = 0; j < 4; ++j) acc[i][j] = 0.f;
            }
            // FMA: acc[i][j] += R[row][d] * Et[k][d]   (reads Et[buf], chunk g)
#pragma unroll
            for (int dd = 0; dd < DT; dd += 4) {
                float4 rv[8];
#pragma unroll
                for (int i = 0; i < 8; ++i)      // wave-uniform addr -> broadcast
                    rv[i] = *(const float4*)&R[ty * 8 + i][dc * DT + dd];
#pragma unroll
                for (int j = 0; j < 4; ++j) {    // stride-5 slots -> conflict-free
                    float4 ev = *(const float4*)&Et[buf][tx + 64 * j][dd];
#pragma unroll
                    for (int i = 0; i < 8; ++i) {
                        acc[i][j] = fmaf(rv[i].x, ev.x, acc[i][j]);
                        acc[i][j] = fmaf(rv[i].y, ev.y, acc[i][j]);
                        acc[i][j] = fmaf(rv[i].z, ev.z, acc[i][j]);
                        acc[i][j] = fmaf(rv[i].w, ev.w, acc[i][j]);
                    }
                }
            }
            if (dc == 15) {  // fold this k-chunk into the running argmin
#pragma unroll
                for (int j = 0; j < 4; ++j) {    // j ascending == k ascending
                    int   kg = kc * KT + j * 64 + tx;
                    float en = En[kg];
#pragma unroll
                    for (int i = 0; i < 8; ++i) {
                        float dv = fmaf(-2.f, acc[i][j], en);
                        if (dv < minv[i]) { minv[i] = dv; mini[i] = kg; }
                    }
                }
            }
        }
        // cross-lane argmin over the wave (ties -> smaller index)
#pragma unroll
        for (int off = 32; off >= 1; off >>= 1) {
#pragma unroll
            for (int i = 0; i < 8; ++i) {
                float ov = __shfl_xor(minv[i], off);
                int   oi = __shfl_xor(mini[i], off);
                if (ov < minv[i] || (ov == minv[i] && oi < mini[i])) {
                    minv[i] = ov; mini[i] = oi;
                }
            }
        }
        if (tx == 0) {
#pragma unroll
            for (int i = 0; i < 8; ++i) amin[ty * 8 + i] = mini[i];
        }
        __syncthreads();
        // epilogue: gather q, loss, STE residual update (reference op-order)
        {
            const float* el = emb + (size_t)l * NK * ND;
            int idx = amin[row_e];
            const float4* q4 = (const float4*)(el + (size_t)idx * ND);
#pragma unroll
            for (int q = 0; q < 8; ++q) {
                int qq = q * 8 + dq;
                float4 qv = q4[qq];
                float4 rv = *(const float4*)&R[row_e][qq * 4];
                float4 df, qs, rn;
                df.x = qv.x - rv.x; df.y = qv.y - rv.y;
                df.z = qv.z - rv.z; df.w = qv.w - rv.w;
                loss_acc = fmaf(df.x, df.x, loss_acc);
                loss_acc = fmaf(df.y, df.y, loss_acc);
                loss_acc = fmaf(df.z, df.z, loss_acc);
                loss_acc = fmaf(df.w, df.w, loss_acc);
                qs.x = rv.x + df.x; qs.y = rv.y + df.y;   // q_st = r + (q - r)
                qs.z = rv.z + df.z; qs.w = rv.w + df.w;
                rn.x = rv.x - qs.x; rn.y = rv.y - qs.y;   // r = r - q_st
                rn.z = rv.z - qs.z; rn.w = rv.w - qs.w;
                *(float4*)&R[row_e][qq * 4] = rn;
            }
            if (dq == 0) codes[(size_t)(brow + row_e) * NL + l] = (float)idx;
        }
        // next chunk's top __syncthreads() orders R writes vs reads
    }
    // quantized_out = x - residual_final (telescoped sum of q_st)
#pragma unroll
    for (int q = 0; q < 8; ++q) {
        int qq = q * 8 + dq;
        float4 xv = x4[qq];
        float4 rv = *(const float4*)&R[row_e][qq * 4];
        float4 ov;
        ov.x = xv.x - rv.x; ov.y = xv.y - rv.y;
        ov.z = xv.z - rv.z; ov.w = xv.w - rv.w;
        ((float4*)(out + (size_t)(brow + row_e) * ND))[qq] = ov;
    }
    // loss: wave reduce, per-wave partials, one atomic per block
#pragma unroll
    for (int off = 32; off >= 1; off >>= 1) loss_acc += __shfl_xor(loss_acc, off);
    if ((tid & 63) == 0) lred[tid >> 6] = loss_acc;
    __syncthreads();
    if (tid == 0) {
        float t = lred[0] + lred[1] + lred[2] + lred[3];
        atomicAdd(loss_slot, t * (0.25f / ((float)NROWTOT * (float)ND)));
    }
}

// ------------------------------------------------------------------ launch ---
extern "C" void kernel_launch(void* const* d_in, const int* in_sizes, int n_in,
                              void* d_out, int out_size, void* d_ws, size_t ws_size,
                              hipStream_t stream) {
    const float* x   = (const float*)d_in[0];   // [32768, 256]
    const float* emb = (const float*)d_in[1];   // [8, 1024, 256]
    float* out   = (float*)d_out;
    float* enorm = (float*)d_ws;                // [8192] floats
    float* loss_slot = out + (size_t)NROWTOT * ND;

    enorm_zero_kernel<<<256, 256, 0, stream>>>(emb, enorm, loss_slot);
    rvq_kernel<<<NROWTOT / ROWS, 256, 0, stream>>>(x, emb, enorm, out);
}